// Round 1
// baseline (1115.288 us; speedup 1.0000x reference)
//
#include <hip/hip_runtime.h>
#include <hip/hip_bf16.h>
#include <stdint.h>

#define N_ATOMS    1000000
#define DIM        128
#define NUM_GRAPHS 100000
#define TILE_ATOMS 64
#define NUM_TILES  (N_ATOMS / TILE_ATOMS)   // 15625
#define LDW        (DIM + 8)                // 136: +8 bf16 pad breaks bank aliasing

typedef __attribute__((ext_vector_type(8))) short short8;   // 8 bf16 (4 VGPRs)
typedef __attribute__((ext_vector_type(4))) float f32x4;    // MFMA accumulator

__device__ __forceinline__ unsigned short f2bf(float x) {
    union { float f; uint32_t u; } v; v.f = x;
    uint32_t u = v.u;
    return (unsigned short)((u + 0x7fffu + ((u >> 16) & 1u)) >> 16);  // RNE
}
__device__ __forceinline__ uint32_t pack2(float a, float b) {
    return (uint32_t)f2bf(a) | ((uint32_t)f2bf(b) << 16);
}
__device__ __forceinline__ float silu(float x) {
    return x / (1.0f + __expf(-x));
}

// Fused: per-atom MLP (GEMM1 -> SiLU -> GEMM2) + sorted-run segment sum via atomics.
// Also writes the fp32 feat passthrough while staging (saves a separate 512MB read).
extern "C" __global__ __launch_bounds__(512, 4)
void mlp_pool_kernel(const float* __restrict__ feat,
                     const int*   __restrict__ batch,
                     const float* __restrict__ W1, const float* __restrict__ b1,
                     const float* __restrict__ W2, const float* __restrict__ b2,
                     float* __restrict__ pooled,
                     float* __restrict__ feat_out)
{
    // Overlay: Xs (17408B) + H1s (17408B); H2 fp32 [64][129] (33024B) reuses both.
    __shared__ __align__(16) char smem[2 * TILE_ATOMS * LDW * 2];
    unsigned short* Xs  = (unsigned short*)smem;                        // [64][136] bf16
    unsigned short* H1s = (unsigned short*)(smem + TILE_ATOMS * LDW * 2); // [64][136] bf16
    float*          H2  = (float*)smem;                                 // [64][129] fp32
    __shared__ float b1s[DIM], b2s[DIM];
    __shared__ int   bids[TILE_ATOMS];

    const int tid  = threadIdx.x;
    const int wave = tid >> 6;      // 0..7 -> owns output cols [wave*16, wave*16+16)
    const int lane = tid & 63;
    const int quad = lane >> 4;     // 0..3
    const int l15  = lane & 15;

    if (tid < DIM) { b1s[tid] = b1[tid]; b2s[tid] = b2[tid]; }

    // B-fragments for W1/W2 held in registers: B[k][n], n = wave*16 + l15,
    // lane holds k = kc*32 + quad*8 + j  (j=0..7)
    short8 w1f[4], w2f[4];
    const int ncol = wave * 16 + l15;
#pragma unroll
    for (int kc = 0; kc < 4; ++kc) {
#pragma unroll
        for (int j = 0; j < 8; ++j) {
            int k = kc * 32 + quad * 8 + j;
            w1f[kc][j] = (short)f2bf(W1[k * DIM + ncol]);
            w2f[kc][j] = (short)f2bf(W2[k * DIM + ncol]);
        }
    }
    __syncthreads();

    for (int tile = blockIdx.x; tile < NUM_TILES; tile += gridDim.x) {
        const size_t base = (size_t)tile * TILE_ATOMS * DIM;

        // ---- stage: global feat -> bf16 LDS tile; also write fp32 passthrough ----
        {
            const float4* src = (const float4*)(feat + base);
            float4*       dst = (float4*)(feat_out + base);
#pragma unroll
            for (int i = 0; i < 4; ++i) {
                int idx = tid + 512 * i;          // float4 index in [0, 2048)
                float4 v = src[idx];
                dst[idx] = v;
                int row  = idx >> 5;              // 32 float4 per row
                int colf = (idx & 31) * 4;
                uint2 pk = { pack2(v.x, v.y), pack2(v.z, v.w) };
                *(uint2*)&Xs[row * LDW + colf] = pk;
            }
            if (tid < TILE_ATOMS) bids[tid] = batch[tile * TILE_ATOMS + tid];
        }
        __syncthreads();

        // ---- GEMM1: H1 = silu(X @ W1 + b1), wave computes cols [wave*16, +16) ----
        f32x4 acc[4];
        const f32x4 zero = {0.f, 0.f, 0.f, 0.f};
#pragma unroll
        for (int g = 0; g < 4; ++g) acc[g] = zero;
#pragma unroll
        for (int g = 0; g < 4; ++g) {
#pragma unroll
            for (int kc = 0; kc < 4; ++kc) {
                short8 a = *(const short8*)&Xs[(g * 16 + l15) * LDW + kc * 32 + quad * 8];
                acc[g] = __builtin_amdgcn_mfma_f32_16x16x32_bf16(a, w1f[kc], acc[g], 0, 0, 0);
            }
        }
        {
            float bias = b1s[ncol];
#pragma unroll
            for (int g = 0; g < 4; ++g) {
#pragma unroll
                for (int r = 0; r < 4; ++r) {
                    int row = g * 16 + quad * 4 + r;
                    H1s[row * LDW + ncol] = f2bf(silu(acc[g][r] + bias));
                }
            }
        }
        __syncthreads();

        // ---- GEMM2: H2 = H1 @ W2 + b2 ----
#pragma unroll
        for (int g = 0; g < 4; ++g) acc[g] = zero;
#pragma unroll
        for (int g = 0; g < 4; ++g) {
#pragma unroll
            for (int kc = 0; kc < 4; ++kc) {
                short8 a = *(const short8*)&H1s[(g * 16 + l15) * LDW + kc * 32 + quad * 8];
                acc[g] = __builtin_amdgcn_mfma_f32_16x16x32_bf16(a, w2f[kc], acc[g], 0, 0, 0);
            }
        }
        __syncthreads();   // all waves done reading H1/X before H2 overlays them
        {
            float bias = b2s[ncol];
#pragma unroll
            for (int g = 0; g < 4; ++g) {
#pragma unroll
                for (int r = 0; r < 4; ++r) {
                    int row = g * 16 + quad * 4 + r;
                    H2[row * 129 + ncol] = acc[g][r] + bias;
                }
            }
        }
        __syncthreads();

        // ---- pooling: batch is sorted -> run-length aggregate, 1 atomic per run ----
        if (tid < DIM) {
            const int colp = tid;
            int   cur = bids[0];
            float sum = 0.f;
#pragma unroll 4
            for (int a2 = 0; a2 < TILE_ATOMS; ++a2) {
                int id = bids[a2];          // wave-uniform -> no divergence
                if (id != cur) {
                    atomicAdd(&pooled[(size_t)cur * DIM + colp], sum);
                    sum = 0.f; cur = id;
                }
                sum += H2[a2 * 129 + colp];
            }
            atomicAdd(&pooled[(size_t)cur * DIM + colp], sum);
        }
        __syncthreads();   // H2 (overlaying Xs) must be consumed before next stage
    }
}

// Graph head: out = silu(pooled @ W3 + b3) @ W4 + b4   (fp32 vector, one wave/graph)
extern "C" __global__ __launch_bounds__(256, 4)
void head_kernel(const float* __restrict__ pooled,
                 const float* __restrict__ W3, const float* __restrict__ b3,
                 const float* __restrict__ W4, const float* __restrict__ b4,
                 float* __restrict__ out)
{
    __shared__ float W3s[DIM * DIM];   // 64 KB
    const int tid = threadIdx.x;
    for (int i = tid; i < DIM * DIM / 4; i += 256)
        ((float4*)W3s)[i] = ((const float4*)W3)[i];
    __syncthreads();

    const int wave = tid >> 6, lane = tid & 63;
    const float w4a = W4[lane], w4b = W4[lane + 64];
    const float b3a = b3[lane], b3b = b3[lane + 64];
    const float b4v = b4[0];

    for (int g = blockIdx.x * 4 + wave; g < NUM_GRAPHS; g += gridDim.x * 4) {
        const float4* p = (const float4*)(pooled + (size_t)g * DIM);
        float a0 = 0.f, a1 = 0.f;
#pragma unroll 8
        for (int k4 = 0; k4 < DIM / 4; ++k4) {
            float4 pv = p[k4];
            int k = k4 * 4;
            a0 += pv.x * W3s[(k    ) * DIM + lane]; a1 += pv.x * W3s[(k    ) * DIM + lane + 64];
            a0 += pv.y * W3s[(k + 1) * DIM + lane]; a1 += pv.y * W3s[(k + 1) * DIM + lane + 64];
            a0 += pv.z * W3s[(k + 2) * DIM + lane]; a1 += pv.z * W3s[(k + 2) * DIM + lane + 64];
            a0 += pv.w * W3s[(k + 3) * DIM + lane]; a1 += pv.w * W3s[(k + 3) * DIM + lane + 64];
        }
        float r = silu(a0 + b3a) * w4a + silu(a1 + b3b) * w4b;
#pragma unroll
        for (int off = 32; off > 0; off >>= 1) r += __shfl_down(r, off, 64);
        if (lane == 0) out[g] = r + b4v;
    }
}

extern "C" void kernel_launch(void* const* d_in, const int* in_sizes, int n_in,
                              void* d_out, int out_size, void* d_ws, size_t ws_size,
                              hipStream_t stream)
{
    const float* feat = (const float*)d_in[0];
    const int*   batch = (const int*)d_in[1];
    const float* W1 = (const float*)d_in[2];
    const float* b1 = (const float*)d_in[3];
    const float* W2 = (const float*)d_in[4];
    const float* b2 = (const float*)d_in[5];
    const float* W3 = (const float*)d_in[6];
    const float* b3 = (const float*)d_in[7];
    const float* W4 = (const float*)d_in[8];
    const float* b4 = (const float*)d_in[9];

    float* out      = (float*)d_out;
    float* feat_out = out + NUM_GRAPHS;           // outputs concatenated: [100000] then [1M*128]
    float* pooled   = (float*)d_ws;               // [100000][128] fp32

    hipMemsetAsync(pooled, 0, (size_t)NUM_GRAPHS * DIM * sizeof(float), stream);
    mlp_pool_kernel<<<1024, 512, 0, stream>>>(feat, batch, W1, b1, W2, b2, pooled, feat_out);
    head_kernel<<<512, 256, 0, stream>>>(pooled, W3, b3, W4, b4, out);
}